// Round 1
// baseline (5977.133 us; speedup 1.0000x reference)
//
#include <hip/hip_runtime.h>
#include <hip/hip_bf16.h>
#include <math.h>

#define NNODES 50000
#define NEDGES 800000
#define FIN 128
#define FH 256
#define NG 64
#define NC 64

// ---------------- degree / counts / norm ----------------

__global__ void degree_kernel(const int* __restrict__ dst, float* __restrict__ deg, int E) {
    int e = blockIdx.x * blockDim.x + threadIdx.x;
    if (e < E) atomicAdd(&deg[dst[e]], 1.0f);
}

__global__ void count_kernel(const int* __restrict__ batch, float* __restrict__ cnt, int Nn) {
    int n = blockIdx.x * blockDim.x + threadIdx.x;
    if (n < Nn) atomicAdd(&cnt[batch[n]], 1.0f);
}

__global__ void rsqrt_kernel(float* __restrict__ deg, int Nn) {
    int n = blockIdx.x * blockDim.x + threadIdx.x;
    if (n < Nn) deg[n] = rsqrtf(deg[n] + 1.0f);
}

// ---------------- f32 tiled GEMM: C[M x 256] = A[M x K] @ B[K x 256] ----------------

#define BM 64
#define BN 64
#define BK 32

__global__ __launch_bounds__(256)
void gemm_kernel(const float* __restrict__ A, const float* __restrict__ B,
                 float* __restrict__ C, int M, int K) {
    __shared__ float As[BM][BK];   // [m][k]: conflict-free writes, broadcast reads
    __shared__ float Bs[BK][BN];   // [k][n]: float4 reads, 2-way (free) write alias
    const int bm = blockIdx.x * BM;
    const int bn = blockIdx.y * BN;
    const int tid = threadIdx.x;
    const int tm = (tid >> 4) << 2;   // 0,4,...,60
    const int tn = (tid & 15) << 2;   // 0,4,...,60
    float acc[4][4] = {};

    for (int k0 = 0; k0 < K; k0 += BK) {
#pragma unroll
        for (int i = 0; i < (BM * BK) / 256; i++) {
            int idx = tid + i * 256;
            int m = idx / BK, k = idx % BK;     // consecutive lanes -> consecutive k (coalesced)
            int gm = bm + m;
            As[m][k] = (gm < M) ? A[(size_t)gm * K + k0 + k] : 0.0f;
        }
#pragma unroll
        for (int i = 0; i < (BK * BN) / 256; i++) {
            int idx = tid + i * 256;
            int k = idx / BN, n = idx % BN;     // consecutive lanes -> consecutive n (coalesced)
            Bs[k][n] = B[(size_t)(k0 + k) * FH + bn + n];
        }
        __syncthreads();
#pragma unroll
        for (int kk = 0; kk < BK; kk++) {
            float a0 = As[tm + 0][kk], a1 = As[tm + 1][kk];
            float a2 = As[tm + 2][kk], a3 = As[tm + 3][kk];
            float4 b = *reinterpret_cast<const float4*>(&Bs[kk][tn]);
            acc[0][0] += a0 * b.x; acc[0][1] += a0 * b.y; acc[0][2] += a0 * b.z; acc[0][3] += a0 * b.w;
            acc[1][0] += a1 * b.x; acc[1][1] += a1 * b.y; acc[1][2] += a1 * b.z; acc[1][3] += a1 * b.w;
            acc[2][0] += a2 * b.x; acc[2][1] += a2 * b.y; acc[2][2] += a2 * b.z; acc[2][3] += a2 * b.w;
            acc[3][0] += a3 * b.x; acc[3][1] += a3 * b.y; acc[3][2] += a3 * b.z; acc[3][3] += a3 * b.w;
        }
        __syncthreads();
    }
#pragma unroll
    for (int i = 0; i < 4; i++) {
        int gm = bm + tm + i;
        if (gm < M) {
            float4 v = {acc[i][0], acc[i][1], acc[i][2], acc[i][3]};
            *reinterpret_cast<float4*>(&C[(size_t)gm * FH + bn + tn]) = v;
        }
    }
}

// ---------------- edge scatter: agg[dst] += t[src] * dinv[src]*dinv[dst] ----------------

__global__ __launch_bounds__(256)
void scatter_kernel(const float* __restrict__ t, const int* __restrict__ src,
                    const int* __restrict__ dst, const float* __restrict__ dinv,
                    float* __restrict__ agg, int E) {
    int e = blockIdx.x * 4 + (threadIdx.x >> 6);   // one wave per edge
    if (e >= E) return;
    int lane = threadIdx.x & 63;
    int s = src[e], d = dst[e];
    float norm = dinv[s] * dinv[d];
    const float4 v = *reinterpret_cast<const float4*>(&t[(size_t)s * FH + lane * 4]);
    float* o = &agg[(size_t)d * FH + lane * 4];
    atomicAdd(o + 0, v.x * norm);
    atomicAdd(o + 1, v.y * norm);
    atomicAdd(o + 2, v.z * norm);
    atomicAdd(o + 3, v.w * norm);
}

// ---------------- finalize: agg = [gelu](agg + t*self_norm + bias) ----------------

__global__ __launch_bounds__(256)
void finalize_kernel(float* __restrict__ agg, const float* __restrict__ t,
                     const float* __restrict__ dinv, const float* __restrict__ bias,
                     int total, int apply_gelu) {
    int idx = blockIdx.x * blockDim.x + threadIdx.x;
    if (idx >= total) return;
    int node = idx >> 8;           // FH == 256
    int c = idx & 255;
    float sn = dinv[node];
    sn *= sn;                       // D^{-1} self-loop weight
    float v = agg[idx] + t[idx] * sn + bias[c];
    if (apply_gelu) v = 0.5f * v * (1.0f + erff(v * 0.70710678118654752f));
    agg[idx] = v;
}

// ---------------- mean-pool (batch is sorted): pooled[g] += sum of rows ----------------

__global__ __launch_bounds__(256)
void pool_kernel(const float* __restrict__ h, const int* __restrict__ batch,
                 float* __restrict__ pooled, int Nn, int npb) {
    int c = threadIdx.x;            // 256 threads = feature columns
    int n0 = blockIdx.x * npb;
    int n1 = min(n0 + npb, Nn);
    if (n0 >= n1) return;
    float acc = 0.0f;
    int cur = batch[n0];
    for (int n = n0; n < n1; n++) {
        int g = batch[n];           // uniform across block (broadcast load)
        if (g != cur) {
            atomicAdd(&pooled[cur * FH + c], acc);
            acc = 0.0f;
            cur = g;
        }
        acc += h[(size_t)n * FH + c];
    }
    atomicAdd(&pooled[cur * FH + c], acc);
}

// ---------------- FC head: out[g] = (pooled[g]/cnt[g]) @ Wfc + bfc ----------------

__global__ __launch_bounds__(64)
void fc_kernel(const float* __restrict__ pooled, const float* __restrict__ cnt,
               const float* __restrict__ Wfc, const float* __restrict__ bfc,
               float* __restrict__ out) {
    int g = blockIdx.x;
    int c2 = threadIdx.x;
    float inv = 1.0f / fmaxf(cnt[g], 1.0f);
    float acc = 0.0f;
    for (int c = 0; c < FH; c++)
        acc += pooled[g * FH + c] * Wfc[c * NC + c2];
    out[g * NC + c2] = acc * inv + bfc[c2];
}

// ---------------- launch ----------------

extern "C" void kernel_launch(void* const* d_in, const int* in_sizes, int n_in,
                              void* d_out, int out_size, void* d_ws, size_t ws_size,
                              hipStream_t stream) {
    const float* x    = (const float*)d_in[0];
    const int*   ei   = (const int*)d_in[1];
    const int*   batch= (const int*)d_in[2];
    const float* W1   = (const float*)d_in[3];
    const float* b1   = (const float*)d_in[4];
    const float* W2   = (const float*)d_in[5];
    const float* b2   = (const float*)d_in[6];
    const float* Wfc  = (const float*)d_in[7];
    const float* bfc  = (const float*)d_in[8];
    float* out = (float*)d_out;

    const int* src = ei;               // edge_index[0]
    const int* dst = ei + NEDGES;      // edge_index[1]

    // workspace layout (floats): 2 feature buffers + dinv + cnt + pooled (~103 MB)
    float* bufT   = (float*)d_ws;                       // t = h @ W        [N,256]
    float* bufA   = bufT + (size_t)NNODES * FH;         // agg / h          [N,256]
    float* dinv   = bufA + (size_t)NNODES * FH;         // deg -> rsqrt     [N]
    float* cnt    = dinv + NNODES;                      // [G]
    float* pooled = cnt + NG;                           // [G,256]

    hipMemsetAsync(dinv,   0, NNODES * sizeof(float), stream);
    hipMemsetAsync(cnt,    0, NG * sizeof(float), stream);
    hipMemsetAsync(pooled, 0, NG * FH * sizeof(float), stream);

    degree_kernel<<<(NEDGES + 255) / 256, 256, 0, stream>>>(dst, dinv, NEDGES);
    count_kernel<<<(NNODES + 255) / 256, 256, 0, stream>>>(batch, cnt, NNODES);
    rsqrt_kernel<<<(NNODES + 255) / 256, 256, 0, stream>>>(dinv, NNODES);

    dim3 ggrid((NNODES + BM - 1) / BM, FH / BN);

    // conv1: t1 = x @ W1 ; agg ; h1 = gelu(agg + t1*self + b1)
    gemm_kernel<<<ggrid, 256, 0, stream>>>(x, W1, bufT, NNODES, FIN);
    hipMemsetAsync(bufA, 0, (size_t)NNODES * FH * sizeof(float), stream);
    scatter_kernel<<<NEDGES / 4, 256, 0, stream>>>(bufT, src, dst, dinv, bufA, NEDGES);
    finalize_kernel<<<(NNODES * FH + 255) / 256, 256, 0, stream>>>(bufA, bufT, dinv, b1,
                                                                   NNODES * FH, 1);

    // conv2: t2 = h1 @ W2 ; agg ; h2 = agg + t2*self + b2
    gemm_kernel<<<ggrid, 256, 0, stream>>>(bufA, W2, bufT, NNODES, FH);
    hipMemsetAsync(bufA, 0, (size_t)NNODES * FH * sizeof(float), stream);
    scatter_kernel<<<NEDGES / 4, 256, 0, stream>>>(bufT, src, dst, dinv, bufA, NEDGES);
    finalize_kernel<<<(NNODES * FH + 255) / 256, 256, 0, stream>>>(bufA, bufT, dinv, b2,
                                                                   NNODES * FH, 0);

    // mean-pool + FC head
    pool_kernel<<<(NNODES + 63) / 64, 256, 0, stream>>>(bufA, batch, pooled, NNODES, 64);
    fc_kernel<<<NG, NC, 0, stream>>>(pooled, cnt, Wfc, bfc, out);
}

// Round 2
// 872.713 us; speedup vs baseline: 6.8489x; 6.8489x over previous
//
#include <hip/hip_runtime.h>
#include <hip/hip_bf16.h>
#include <math.h>

#define NNODES 50000
#define NEDGES 800000
#define FIN 128
#define FH 256
#define NG 64
#define NC 64
#define SCAN_NB ((NNODES + 255) / 256)   // 196 blocks (<= 256, fits one scan block)

// ---------------- degree / counts / norm ----------------

__global__ void degree_kernel(const int* __restrict__ dst, int* __restrict__ degi, int E) {
    int e = blockIdx.x * blockDim.x + threadIdx.x;
    if (e < E) atomicAdd(&degi[dst[e]], 1);
}

__global__ void count_kernel(const int* __restrict__ batch, float* __restrict__ cnt, int Nn) {
    int n = blockIdx.x * blockDim.x + threadIdx.x;
    if (n < Nn) atomicAdd(&cnt[batch[n]], 1.0f);
}

__global__ void dinv_kernel(const int* __restrict__ degi, float* __restrict__ dinv, int Nn) {
    int n = blockIdx.x * blockDim.x + threadIdx.x;
    if (n < Nn) dinv[n] = rsqrtf((float)degi[n] + 1.0f);
}

// ---------------- 2-level exclusive scan over degi -> row_start ----------------

__global__ __launch_bounds__(256)
void scan_block_kernel(const int* __restrict__ degi, int* __restrict__ local_ex,
                       int* __restrict__ partial, int Nn) {
    __shared__ int s[256];
    int i = blockIdx.x * 256 + threadIdx.x;
    int v = (i < Nn) ? degi[i] : 0;
    s[threadIdx.x] = v;
    __syncthreads();
#pragma unroll
    for (int off = 1; off < 256; off <<= 1) {
        int t = (threadIdx.x >= off) ? s[threadIdx.x - off] : 0;
        __syncthreads();
        s[threadIdx.x] += t;
        __syncthreads();
    }
    if (i < Nn) local_ex[i] = s[threadIdx.x] - v;   // exclusive within block
    if (threadIdx.x == 255) partial[blockIdx.x] = s[255];
}

__global__ __launch_bounds__(256)
void scan_partial_kernel(int* __restrict__ partial, int nb) {
    __shared__ int s[256];
    int v = (threadIdx.x < nb) ? partial[threadIdx.x] : 0;
    s[threadIdx.x] = v;
    __syncthreads();
#pragma unroll
    for (int off = 1; off < 256; off <<= 1) {
        int t = (threadIdx.x >= off) ? s[threadIdx.x - off] : 0;
        __syncthreads();
        s[threadIdx.x] += t;
        __syncthreads();
    }
    if (threadIdx.x < nb) partial[threadIdx.x] = s[threadIdx.x] - v;  // exclusive
}

__global__ void add_offsets_kernel(int* __restrict__ row_start, const int* __restrict__ local_ex,
                                   const int* __restrict__ partial, int Nn) {
    int i = blockIdx.x * 256 + threadIdx.x;
    if (i < Nn) row_start[i] = local_ex[i] + partial[blockIdx.x];
}

// ---------------- edge placement: CSR by dst, with precomputed edge norm ----------------

__global__ void edge_place_kernel(const int* __restrict__ src, const int* __restrict__ dst,
                                  const int* __restrict__ row_start, int* __restrict__ cursor,
                                  const float* __restrict__ dinv,
                                  int* __restrict__ esrc, float* __restrict__ enorm, int E) {
    int e = blockIdx.x * blockDim.x + threadIdx.x;
    if (e >= E) return;
    int s = src[e], d = dst[e];
    int pos = row_start[d] + atomicAdd(&cursor[d], 1);
    esrc[pos] = s;
    enorm[pos] = dinv[s] * dinv[d];
}

// ---------------- f32 tiled GEMM: C[M x 256] = A[M x K] @ B[K x 256] ----------------

#define BM 64
#define BN 64
#define BK 32

__global__ __launch_bounds__(256)
void gemm_kernel(const float* __restrict__ A, const float* __restrict__ B,
                 float* __restrict__ C, int M, int K) {
    __shared__ float As[BM][BK];
    __shared__ float Bs[BK][BN];
    const int bm = blockIdx.x * BM;
    const int bn = blockIdx.y * BN;
    const int tid = threadIdx.x;
    const int tm = (tid >> 4) << 2;
    const int tn = (tid & 15) << 2;
    float acc[4][4] = {};

    for (int k0 = 0; k0 < K; k0 += BK) {
#pragma unroll
        for (int i = 0; i < (BM * BK) / 256; i++) {
            int idx = tid + i * 256;
            int m = idx / BK, k = idx % BK;
            int gm = bm + m;
            As[m][k] = (gm < M) ? A[(size_t)gm * K + k0 + k] : 0.0f;
        }
#pragma unroll
        for (int i = 0; i < (BK * BN) / 256; i++) {
            int idx = tid + i * 256;
            int k = idx / BN, n = idx % BN;
            Bs[k][n] = B[(size_t)(k0 + k) * FH + bn + n];
        }
        __syncthreads();
#pragma unroll
        for (int kk = 0; kk < BK; kk++) {
            float a0 = As[tm + 0][kk], a1 = As[tm + 1][kk];
            float a2 = As[tm + 2][kk], a3 = As[tm + 3][kk];
            float4 b = *reinterpret_cast<const float4*>(&Bs[kk][tn]);
            acc[0][0] += a0 * b.x; acc[0][1] += a0 * b.y; acc[0][2] += a0 * b.z; acc[0][3] += a0 * b.w;
            acc[1][0] += a1 * b.x; acc[1][1] += a1 * b.y; acc[1][2] += a1 * b.z; acc[1][3] += a1 * b.w;
            acc[2][0] += a2 * b.x; acc[2][1] += a2 * b.y; acc[2][2] += a2 * b.z; acc[2][3] += a2 * b.w;
            acc[3][0] += a3 * b.x; acc[3][1] += a3 * b.y; acc[3][2] += a3 * b.z; acc[3][3] += a3 * b.w;
        }
        __syncthreads();
    }
#pragma unroll
    for (int i = 0; i < 4; i++) {
        int gm = bm + tm + i;
        if (gm < M) {
            float4 v = {acc[i][0], acc[i][1], acc[i][2], acc[i][3]};
            *reinterpret_cast<float4*>(&C[(size_t)gm * FH + bn + tn]) = v;
        }
    }
}

// ---------------- CSR gather + finalize: h[n] = [gelu](sum_e t[src]*norm + t[n]*sn + b) ----------------

__global__ __launch_bounds__(256)
void gather_kernel(const float* __restrict__ t, const int* __restrict__ esrc,
                   const float* __restrict__ enorm, const int* __restrict__ row_start,
                   const int* __restrict__ degi, const float* __restrict__ dinv,
                   const float* __restrict__ bias, float* __restrict__ h,
                   int Nn, int apply_gelu) {
    int node = blockIdx.x * 4 + (threadIdx.x >> 6);   // one wave per node
    if (node >= Nn) return;
    int lane = threadIdx.x & 63;
    int st = row_start[node];
    int cnt = degi[node];
    float ax = 0.0f, ay = 0.0f, az = 0.0f, aw = 0.0f;
    int j = 0;
    for (; j + 1 < cnt; j += 2) {                     // 2-way ILP on the row loads
        int   s0 = esrc[st + j],     s1 = esrc[st + j + 1];
        float n0 = enorm[st + j],    n1 = enorm[st + j + 1];
        float4 v0 = *reinterpret_cast<const float4*>(&t[(size_t)s0 * FH + lane * 4]);
        float4 v1 = *reinterpret_cast<const float4*>(&t[(size_t)s1 * FH + lane * 4]);
        ax += v0.x * n0 + v1.x * n1;
        ay += v0.y * n0 + v1.y * n1;
        az += v0.z * n0 + v1.z * n1;
        aw += v0.w * n0 + v1.w * n1;
    }
    if (j < cnt) {
        int   s0 = esrc[st + j];
        float n0 = enorm[st + j];
        float4 v0 = *reinterpret_cast<const float4*>(&t[(size_t)s0 * FH + lane * 4]);
        ax += v0.x * n0; ay += v0.y * n0; az += v0.z * n0; aw += v0.w * n0;
    }
    float sn = dinv[node];
    sn *= sn;                                          // D^{-1} self-loop weight
    float4 tv = *reinterpret_cast<const float4*>(&t[(size_t)node * FH + lane * 4]);
    float4 bv = *reinterpret_cast<const float4*>(&bias[lane * 4]);
    float4 o;
    o.x = ax + tv.x * sn + bv.x;
    o.y = ay + tv.y * sn + bv.y;
    o.z = az + tv.z * sn + bv.z;
    o.w = aw + tv.w * sn + bv.w;
    if (apply_gelu) {
        o.x = 0.5f * o.x * (1.0f + erff(o.x * 0.70710678f));
        o.y = 0.5f * o.y * (1.0f + erff(o.y * 0.70710678f));
        o.z = 0.5f * o.z * (1.0f + erff(o.z * 0.70710678f));
        o.w = 0.5f * o.w * (1.0f + erff(o.w * 0.70710678f));
    }
    *reinterpret_cast<float4*>(&h[(size_t)node * FH + lane * 4]) = o;
}

// ---------------- mean-pool (batch sorted): pooled[g] += run sums ----------------

__global__ __launch_bounds__(256)
void pool_kernel(const float* __restrict__ h, const int* __restrict__ batch,
                 float* __restrict__ pooled, int Nn, int npb) {
    int c = threadIdx.x;
    int n0 = blockIdx.x * npb;
    int n1 = min(n0 + npb, Nn);
    if (n0 >= n1) return;
    float acc = 0.0f;
    int cur = batch[n0];
    for (int n = n0; n < n1; n++) {
        int g = batch[n];
        if (g != cur) {
            atomicAdd(&pooled[cur * FH + c], acc);
            acc = 0.0f;
            cur = g;
        }
        acc += h[(size_t)n * FH + c];
    }
    atomicAdd(&pooled[cur * FH + c], acc);
}

// ---------------- FC head ----------------

__global__ __launch_bounds__(64)
void fc_kernel(const float* __restrict__ pooled, const float* __restrict__ cnt,
               const float* __restrict__ Wfc, const float* __restrict__ bfc,
               float* __restrict__ out) {
    int g = blockIdx.x;
    int c2 = threadIdx.x;
    float inv = 1.0f / fmaxf(cnt[g], 1.0f);
    float acc = 0.0f;
    for (int c = 0; c < FH; c++)
        acc += pooled[g * FH + c] * Wfc[c * NC + c2];
    out[g * NC + c2] = acc * inv + bfc[c2];
}

// ---------------- launch ----------------

extern "C" void kernel_launch(void* const* d_in, const int* in_sizes, int n_in,
                              void* d_out, int out_size, void* d_ws, size_t ws_size,
                              hipStream_t stream) {
    const float* x    = (const float*)d_in[0];
    const int*   ei   = (const int*)d_in[1];
    const int*   batch= (const int*)d_in[2];
    const float* W1   = (const float*)d_in[3];
    const float* b1   = (const float*)d_in[4];
    const float* W2   = (const float*)d_in[5];
    const float* b2   = (const float*)d_in[6];
    const float* Wfc  = (const float*)d_in[7];
    const float* bfc  = (const float*)d_in[8];
    float* out = (float*)d_out;

    const int* src = ei;               // edge_index[0]
    const int* dst = ei + NEDGES;      // edge_index[1]

    // workspace layout: 2 feature buffers + CSR + small vectors (~110 MB)
    float* bufT     = (float*)d_ws;                     // t = h @ W        [N,256]
    float* bufA     = bufT + (size_t)NNODES * FH;       // h (gather out)   [N,256]
    int*   esrc     = (int*)(bufA + (size_t)NNODES * FH); // [E]
    float* enorm    = (float*)(esrc + NEDGES);          // [E]
    int*   degi     = (int*)(enorm + NEDGES);           // [N]
    int*   row_start= degi + NNODES;                    // [N]
    int*   local_ex = row_start + NNODES;               // [N]
    int*   cursor   = local_ex + NNODES;                // [N]
    int*   partial  = cursor + NNODES;                  // [SCAN_NB]
    float* dinv     = (float*)(partial + 256);          // [N]
    float* cnt      = dinv + NNODES;                    // [G]
    float* pooled   = cnt + NG;                         // [G,256]

    hipMemsetAsync(degi,   0, NNODES * sizeof(int), stream);
    hipMemsetAsync(cursor, 0, NNODES * sizeof(int), stream);
    hipMemsetAsync(cnt,    0, NG * sizeof(float), stream);
    hipMemsetAsync(pooled, 0, NG * FH * sizeof(float), stream);

    // ---- CSR build (reused by both convs) ----
    degree_kernel<<<(NEDGES + 255) / 256, 256, 0, stream>>>(dst, degi, NEDGES);
    count_kernel<<<(NNODES + 255) / 256, 256, 0, stream>>>(batch, cnt, NNODES);
    dinv_kernel<<<(NNODES + 255) / 256, 256, 0, stream>>>(degi, dinv, NNODES);
    scan_block_kernel<<<SCAN_NB, 256, 0, stream>>>(degi, local_ex, partial, NNODES);
    scan_partial_kernel<<<1, 256, 0, stream>>>(partial, SCAN_NB);
    add_offsets_kernel<<<SCAN_NB, 256, 0, stream>>>(row_start, local_ex, partial, NNODES);
    edge_place_kernel<<<(NEDGES + 255) / 256, 256, 0, stream>>>(src, dst, row_start, cursor,
                                                                dinv, esrc, enorm, NEDGES);

    dim3 ggrid((NNODES + BM - 1) / BM, FH / BN);
    int gather_blocks = (NNODES + 3) / 4;

    // conv1: t1 = x @ W1 ; h1 = gelu(gather(t1) + t1*self + b1)
    gemm_kernel<<<ggrid, 256, 0, stream>>>(x, W1, bufT, NNODES, FIN);
    gather_kernel<<<gather_blocks, 256, 0, stream>>>(bufT, esrc, enorm, row_start, degi,
                                                     dinv, b1, bufA, NNODES, 1);

    // conv2: t2 = h1 @ W2 ; h2 = gather(t2) + t2*self + b2
    gemm_kernel<<<ggrid, 256, 0, stream>>>(bufA, W2, bufT, NNODES, FH);
    gather_kernel<<<gather_blocks, 256, 0, stream>>>(bufT, esrc, enorm, row_start, degi,
                                                     dinv, b2, bufA, NNODES, 0);

    // mean-pool + FC head
    pool_kernel<<<(NNODES + 63) / 64, 256, 0, stream>>>(bufA, batch, pooled, NNODES, 64);
    fc_kernel<<<NG, NC, 0, stream>>>(pooled, cnt, Wfc, bfc, out);
}

// Round 3
// 644.740 us; speedup vs baseline: 9.2706x; 1.3536x over previous
//
#include <hip/hip_runtime.h>
#include <hip/hip_bf16.h>
#include <math.h>

#define NNODES 50000
#define NEDGES 800000
#define FIN 128
#define FH 256
#define NG 64
#define NC 64
#define SCAN_NB ((NNODES + 255) / 256)   // 196 blocks (<= 256, fits one scan block)

// ---------------- degree / norm ----------------

__global__ void degree_kernel(const int* __restrict__ dst, int* __restrict__ degi, int E) {
    int e = blockIdx.x * blockDim.x + threadIdx.x;
    if (e < E) atomicAdd(&degi[dst[e]], 1);
}

__global__ void dinv_kernel(const int* __restrict__ degi, float* __restrict__ dinv, int Nn) {
    int n = blockIdx.x * blockDim.x + threadIdx.x;
    if (n < Nn) dinv[n] = rsqrtf((float)degi[n] + 1.0f);
}

// ---------------- per-graph node counts via binary search (batch is sorted) ----------------

__global__ __launch_bounds__(64)
void graph_bounds_kernel(const int* __restrict__ batch, float* __restrict__ cnt) {
    int g = threadIdx.x;    // 0..63
    int lo = 0, hi = NNODES;
    while (lo < hi) { int mid = (lo + hi) >> 1; if (batch[mid] < g) lo = mid + 1; else hi = mid; }
    int a = lo;
    lo = 0; hi = NNODES;
    while (lo < hi) { int mid = (lo + hi) >> 1; if (batch[mid] < g + 1) lo = mid + 1; else hi = mid; }
    cnt[g] = (float)(lo - a);
}

// ---------------- 2-level exclusive scan over degi -> row_start ----------------

__global__ __launch_bounds__(256)
void scan_block_kernel(const int* __restrict__ degi, int* __restrict__ local_ex,
                       int* __restrict__ partial, int Nn) {
    __shared__ int s[256];
    int i = blockIdx.x * 256 + threadIdx.x;
    int v = (i < Nn) ? degi[i] : 0;
    s[threadIdx.x] = v;
    __syncthreads();
#pragma unroll
    for (int off = 1; off < 256; off <<= 1) {
        int t = (threadIdx.x >= off) ? s[threadIdx.x - off] : 0;
        __syncthreads();
        s[threadIdx.x] += t;
        __syncthreads();
    }
    if (i < Nn) local_ex[i] = s[threadIdx.x] - v;
    if (threadIdx.x == 255) partial[blockIdx.x] = s[255];
}

__global__ __launch_bounds__(256)
void scan_partial_kernel(int* __restrict__ partial, int nb) {
    __shared__ int s[256];
    int v = (threadIdx.x < nb) ? partial[threadIdx.x] : 0;
    s[threadIdx.x] = v;
    __syncthreads();
#pragma unroll
    for (int off = 1; off < 256; off <<= 1) {
        int t = (threadIdx.x >= off) ? s[threadIdx.x - off] : 0;
        __syncthreads();
        s[threadIdx.x] += t;
        __syncthreads();
    }
    if (threadIdx.x < nb) partial[threadIdx.x] = s[threadIdx.x] - v;
}

__global__ void add_offsets_kernel(int* __restrict__ row_start, const int* __restrict__ local_ex,
                                   const int* __restrict__ partial, int Nn) {
    int i = blockIdx.x * 256 + threadIdx.x;
    if (i < Nn) row_start[i] = local_ex[i] + partial[blockIdx.x];
}

// ---------------- edge placement: CSR by dst, with precomputed edge norm ----------------

__global__ void edge_place_kernel(const int* __restrict__ src, const int* __restrict__ dst,
                                  const int* __restrict__ row_start, int* __restrict__ cursor,
                                  const float* __restrict__ dinv,
                                  int* __restrict__ esrc, float* __restrict__ enorm, int E) {
    int e = blockIdx.x * blockDim.x + threadIdx.x;
    if (e >= E) return;
    int s = src[e], d = dst[e];
    int pos = row_start[d] + atomicAdd(&cursor[d], 1);
    esrc[pos] = s;
    enorm[pos] = dinv[s] * dinv[d];
}

// ---------------- f32 tiled GEMM: C[M x 256] = A[M x K] @ B[K x 256] (+opt bias+gelu) ----------------

#define BM 64
#define BN 64
#define BK 32

__global__ __launch_bounds__(256)
void gemm_kernel(const float* __restrict__ A, const float* __restrict__ B,
                 float* __restrict__ C, const float* __restrict__ bias,
                 int M, int K, int fuse_bias_gelu) {
    __shared__ float As[BM][BK];
    __shared__ float Bs[BK][BN];
    const int bm = blockIdx.x * BM;
    const int bn = blockIdx.y * BN;
    const int tid = threadIdx.x;
    const int tm = (tid >> 4) << 2;
    const int tn = (tid & 15) << 2;
    float acc[4][4] = {};

    for (int k0 = 0; k0 < K; k0 += BK) {
#pragma unroll
        for (int i = 0; i < (BM * BK) / 256; i++) {
            int idx = tid + i * 256;
            int m = idx / BK, k = idx % BK;
            int gm = bm + m;
            As[m][k] = (gm < M) ? A[(size_t)gm * K + k0 + k] : 0.0f;
        }
#pragma unroll
        for (int i = 0; i < (BK * BN) / 256; i++) {
            int idx = tid + i * 256;
            int k = idx / BN, n = idx % BN;
            Bs[k][n] = B[(size_t)(k0 + k) * FH + bn + n];
        }
        __syncthreads();
#pragma unroll
        for (int kk = 0; kk < BK; kk++) {
            float a0 = As[tm + 0][kk], a1 = As[tm + 1][kk];
            float a2 = As[tm + 2][kk], a3 = As[tm + 3][kk];
            float4 b = *reinterpret_cast<const float4*>(&Bs[kk][tn]);
            acc[0][0] += a0 * b.x; acc[0][1] += a0 * b.y; acc[0][2] += a0 * b.z; acc[0][3] += a0 * b.w;
            acc[1][0] += a1 * b.x; acc[1][1] += a1 * b.y; acc[1][2] += a1 * b.z; acc[1][3] += a1 * b.w;
            acc[2][0] += a2 * b.x; acc[2][1] += a2 * b.y; acc[2][2] += a2 * b.z; acc[2][3] += a2 * b.w;
            acc[3][0] += a3 * b.x; acc[3][1] += a3 * b.y; acc[3][2] += a3 * b.z; acc[3][3] += a3 * b.w;
        }
        __syncthreads();
    }
    float4 bv = *reinterpret_cast<const float4*>(&bias[bn + tn]);
#pragma unroll
    for (int i = 0; i < 4; i++) {
        int gm = bm + tm + i;
        if (gm < M) {
            float4 v = {acc[i][0] , acc[i][1], acc[i][2], acc[i][3]};
            if (fuse_bias_gelu) {
                v.x += bv.x; v.y += bv.y; v.z += bv.z; v.w += bv.w;
                v.x = 0.5f * v.x * (1.0f + erff(v.x * 0.70710678118654752f));
                v.y = 0.5f * v.y * (1.0f + erff(v.y * 0.70710678118654752f));
                v.z = 0.5f * v.z * (1.0f + erff(v.z * 0.70710678118654752f));
                v.w = 0.5f * v.w * (1.0f + erff(v.w * 0.70710678118654752f));
            }
            *reinterpret_cast<float4*>(&C[(size_t)gm * FH + bn + tn]) = v;
        }
    }
}

// ---------------- CSR gather, 128 feats (conv1 pre-transform): z[n] = sum + x[n]*sn ----------------

__global__ __launch_bounds__(256)
void gather128_kernel(const float* __restrict__ x, const int* __restrict__ esrc,
                      const float* __restrict__ enorm, const int* __restrict__ row_start,
                      const int* __restrict__ degi, const float* __restrict__ dinv,
                      float* __restrict__ z, int Nn) {
    int node = blockIdx.x * 4 + (threadIdx.x >> 6);   // one wave per node
    if (node >= Nn) return;
    int lane = threadIdx.x & 63;
    int st = row_start[node];
    int cnt = degi[node];
    float ax = 0.0f, ay = 0.0f;
    int j = 0;
    for (; j + 1 < cnt; j += 2) {
        int   s0 = esrc[st + j],  s1 = esrc[st + j + 1];
        float n0 = enorm[st + j], n1 = enorm[st + j + 1];
        float2 v0 = *reinterpret_cast<const float2*>(&x[(size_t)s0 * FIN + lane * 2]);
        float2 v1 = *reinterpret_cast<const float2*>(&x[(size_t)s1 * FIN + lane * 2]);
        ax += v0.x * n0 + v1.x * n1;
        ay += v0.y * n0 + v1.y * n1;
    }
    if (j < cnt) {
        int   s0 = esrc[st + j];
        float n0 = enorm[st + j];
        float2 v0 = *reinterpret_cast<const float2*>(&x[(size_t)s0 * FIN + lane * 2]);
        ax += v0.x * n0; ay += v0.y * n0;
    }
    float sn = dinv[node];
    sn *= sn;
    float2 xv = *reinterpret_cast<const float2*>(&x[(size_t)node * FIN + lane * 2]);
    float2 o = {ax + xv.x * sn, ay + xv.y * sn};
    *reinterpret_cast<float2*>(&z[(size_t)node * FIN + lane * 2]) = o;
}

// ---------------- CSR gather, 256 feats (conv2 post-transform) + self + bias ----------------

__global__ __launch_bounds__(256)
void gather256_kernel(const float* __restrict__ t, const int* __restrict__ esrc,
                      const float* __restrict__ enorm, const int* __restrict__ row_start,
                      const int* __restrict__ degi, const float* __restrict__ dinv,
                      const float* __restrict__ bias, float* __restrict__ h, int Nn) {
    int node = blockIdx.x * 4 + (threadIdx.x >> 6);   // one wave per node
    if (node >= Nn) return;
    int lane = threadIdx.x & 63;
    int st = row_start[node];
    int cnt = degi[node];
    float ax = 0.0f, ay = 0.0f, az = 0.0f, aw = 0.0f;
    int j = 0;
    for (; j + 1 < cnt; j += 2) {
        int   s0 = esrc[st + j],  s1 = esrc[st + j + 1];
        float n0 = enorm[st + j], n1 = enorm[st + j + 1];
        float4 v0 = *reinterpret_cast<const float4*>(&t[(size_t)s0 * FH + lane * 4]);
        float4 v1 = *reinterpret_cast<const float4*>(&t[(size_t)s1 * FH + lane * 4]);
        ax += v0.x * n0 + v1.x * n1;
        ay += v0.y * n0 + v1.y * n1;
        az += v0.z * n0 + v1.z * n1;
        aw += v0.w * n0 + v1.w * n1;
    }
    if (j < cnt) {
        int   s0 = esrc[st + j];
        float n0 = enorm[st + j];
        float4 v0 = *reinterpret_cast<const float4*>(&t[(size_t)s0 * FH + lane * 4]);
        ax += v0.x * n0; ay += v0.y * n0; az += v0.z * n0; aw += v0.w * n0;
    }
    float sn = dinv[node];
    sn *= sn;
    float4 tv = *reinterpret_cast<const float4*>(&t[(size_t)node * FH + lane * 4]);
    float4 bv = *reinterpret_cast<const float4*>(&bias[lane * 4]);
    float4 o = {ax + tv.x * sn + bv.x, ay + tv.y * sn + bv.y,
                az + tv.z * sn + bv.z, aw + tv.w * sn + bv.w};
    *reinterpret_cast<float4*>(&h[(size_t)node * FH + lane * 4]) = o;
}

// ---------------- mean-pool (batch sorted): pooled[g] += run sums ----------------

__global__ __launch_bounds__(256)
void pool_kernel(const float* __restrict__ h, const int* __restrict__ batch,
                 float* __restrict__ pooled, int Nn, int npb) {
    int c = threadIdx.x;
    int n0 = blockIdx.x * npb;
    int n1 = min(n0 + npb, Nn);
    if (n0 >= n1) return;
    float acc = 0.0f;
    int cur = batch[n0];
    for (int n = n0; n < n1; n++) {
        int g = batch[n];
        if (g != cur) {
            atomicAdd(&pooled[cur * FH + c], acc);
            acc = 0.0f;
            cur = g;
        }
        acc += h[(size_t)n * FH + c];
    }
    atomicAdd(&pooled[cur * FH + c], acc);
}

// ---------------- FC head ----------------

__global__ __launch_bounds__(64)
void fc_kernel(const float* __restrict__ pooled, const float* __restrict__ cnt,
               const float* __restrict__ Wfc, const float* __restrict__ bfc,
               float* __restrict__ out) {
    int g = blockIdx.x;
    int c2 = threadIdx.x;
    float inv = 1.0f / fmaxf(cnt[g], 1.0f);
    float acc = 0.0f;
    for (int c = 0; c < FH; c++)
        acc += pooled[g * FH + c] * Wfc[c * NC + c2];
    out[g * NC + c2] = acc * inv + bfc[c2];
}

// ---------------- launch ----------------

extern "C" void kernel_launch(void* const* d_in, const int* in_sizes, int n_in,
                              void* d_out, int out_size, void* d_ws, size_t ws_size,
                              hipStream_t stream) {
    const float* x    = (const float*)d_in[0];
    const int*   ei   = (const int*)d_in[1];
    const int*   batch= (const int*)d_in[2];
    const float* W1   = (const float*)d_in[3];
    const float* b1   = (const float*)d_in[4];
    const float* W2   = (const float*)d_in[5];
    const float* b2   = (const float*)d_in[6];
    const float* Wfc  = (const float*)d_in[7];
    const float* bfc  = (const float*)d_in[8];
    float* out = (float*)d_out;

    const int* src = ei;               // edge_index[0]
    const int* dst = ei + NEDGES;      // edge_index[1]

    // workspace layout: 2 feature buffers + CSR + small vectors (~110 MB)
    // aggX [N,128] aliases bufT's first half (dead at the time aggX is live).
    float* bufT     = (float*)d_ws;                       // t2 [N,256]; aggX [N,128] early
    float* bufA     = bufT + (size_t)NNODES * FH;         // h1 / h2 [N,256]
    int*   esrc     = (int*)(bufA + (size_t)NNODES * FH); // [E]
    float* enorm    = (float*)(esrc + NEDGES);            // [E]
    int*   degi     = (int*)(enorm + NEDGES);             // [N]
    int*   row_start= degi + NNODES;                      // [N]
    int*   local_ex = row_start + NNODES;                 // [N]
    int*   cursor   = local_ex + NNODES;                  // [N]
    int*   partial  = cursor + NNODES;                    // [256]
    float* dinv     = (float*)(partial + 256);            // [N]
    float* cnt      = dinv + NNODES;                      // [G]
    float* pooled   = cnt + NG;                           // [G,256]
    float* aggX     = bufT;                               // [N,128] alias

    hipMemsetAsync(degi,   0, NNODES * sizeof(int), stream);
    hipMemsetAsync(cursor, 0, NNODES * sizeof(int), stream);
    hipMemsetAsync(pooled, 0, NG * FH * sizeof(float), stream);

    // ---- CSR build (reused by both convs) ----
    degree_kernel<<<(NEDGES + 255) / 256, 256, 0, stream>>>(dst, degi, NEDGES);
    graph_bounds_kernel<<<1, 64, 0, stream>>>(batch, cnt);
    dinv_kernel<<<(NNODES + 255) / 256, 256, 0, stream>>>(degi, dinv, NNODES);
    scan_block_kernel<<<SCAN_NB, 256, 0, stream>>>(degi, local_ex, partial, NNODES);
    scan_partial_kernel<<<1, 256, 0, stream>>>(partial, SCAN_NB);
    add_offsets_kernel<<<SCAN_NB, 256, 0, stream>>>(row_start, local_ex, partial, NNODES);
    edge_place_kernel<<<(NEDGES + 255) / 256, 256, 0, stream>>>(src, dst, row_start, cursor,
                                                                dinv, esrc, enorm, NEDGES);

    dim3 ggrid((NNODES + BM - 1) / BM, FH / BN);
    int gather_blocks = (NNODES + 3) / 4;

    // conv1 (aggregate-first): z = Ahat*x ; h1 = gelu(z @ W1 + b1)
    gather128_kernel<<<gather_blocks, 256, 0, stream>>>(x, esrc, enorm, row_start, degi,
                                                        dinv, aggX, NNODES);
    gemm_kernel<<<ggrid, 256, 0, stream>>>(aggX, W1, bufA, b1, NNODES, FIN, 1);

    // conv2 (transform-first): t2 = h1 @ W2 ; h2 = Ahat*t2 + b2
    gemm_kernel<<<ggrid, 256, 0, stream>>>(bufA, W2, bufT, b2, NNODES, FH, 0);
    gather256_kernel<<<gather_blocks, 256, 0, stream>>>(bufT, esrc, enorm, row_start, degi,
                                                        dinv, b2, bufA, NNODES);

    // mean-pool + FC head
    pool_kernel<<<(NNODES + 63) / 64, 256, 0, stream>>>(bufA, batch, pooled, NNODES, 64);
    fc_kernel<<<NG, NC, 0, stream>>>(pooled, cnt, Wfc, bfc, out);
}

// Round 4
// 515.431 us; speedup vs baseline: 11.5964x; 1.2509x over previous
//
#include <hip/hip_runtime.h>
#include <hip/hip_bf16.h>
#include <math.h>

#define NNODES 50000
#define NEDGES 800000
#define FIN 128
#define FH 256
#define NG 64
#define NC 64
#define SCAN_NB ((NNODES + 255) / 256)

typedef unsigned short bhalf;
typedef __attribute__((ext_vector_type(8))) short bf16x8;
typedef __attribute__((ext_vector_type(4))) float f32x4;

__device__ inline bhalf f2bf_rn(float f) {
    unsigned int u = __float_as_uint(f);
    u += 0x7FFFu + ((u >> 16) & 1u);      // round-to-nearest-even
    return (bhalf)(u >> 16);
}
__device__ inline float bf2f(bhalf h) { return __uint_as_float(((unsigned int)h) << 16); }

// ---------------- degree / norm ----------------

__global__ void degree_kernel(const int* __restrict__ dst, int* __restrict__ degi, int E) {
    int e = blockIdx.x * blockDim.x + threadIdx.x;
    if (e < E) atomicAdd(&degi[dst[e]], 1);
}

__global__ void dinv_kernel(const int* __restrict__ degi, float* __restrict__ dinv, int Nn) {
    int n = blockIdx.x * blockDim.x + threadIdx.x;
    if (n < Nn) dinv[n] = rsqrtf((float)degi[n] + 1.0f);
}

// ---------------- per-graph node counts via binary search (batch is sorted) ----------------

__global__ __launch_bounds__(64)
void graph_bounds_kernel(const int* __restrict__ batch, float* __restrict__ cnt) {
    int g = threadIdx.x;
    int lo = 0, hi = NNODES;
    while (lo < hi) { int mid = (lo + hi) >> 1; if (batch[mid] < g) lo = mid + 1; else hi = mid; }
    int a = lo;
    lo = 0; hi = NNODES;
    while (lo < hi) { int mid = (lo + hi) >> 1; if (batch[mid] < g + 1) lo = mid + 1; else hi = mid; }
    cnt[g] = (float)(lo - a);
}

// ---------------- 2-level exclusive scan over degi -> row_start ----------------

__global__ __launch_bounds__(256)
void scan_block_kernel(const int* __restrict__ degi, int* __restrict__ local_ex,
                       int* __restrict__ partial, int Nn) {
    __shared__ int s[256];
    int i = blockIdx.x * 256 + threadIdx.x;
    int v = (i < Nn) ? degi[i] : 0;
    s[threadIdx.x] = v;
    __syncthreads();
#pragma unroll
    for (int off = 1; off < 256; off <<= 1) {
        int t = (threadIdx.x >= off) ? s[threadIdx.x - off] : 0;
        __syncthreads();
        s[threadIdx.x] += t;
        __syncthreads();
    }
    if (i < Nn) local_ex[i] = s[threadIdx.x] - v;
    if (threadIdx.x == 255) partial[blockIdx.x] = s[255];
}

__global__ __launch_bounds__(256)
void scan_partial_kernel(int* __restrict__ partial, int nb) {
    __shared__ int s[256];
    int v = (threadIdx.x < nb) ? partial[threadIdx.x] : 0;
    s[threadIdx.x] = v;
    __syncthreads();
#pragma unroll
    for (int off = 1; off < 256; off <<= 1) {
        int t = (threadIdx.x >= off) ? s[threadIdx.x - off] : 0;
        __syncthreads();
        s[threadIdx.x] += t;
        __syncthreads();
    }
    if (threadIdx.x < nb) partial[threadIdx.x] = s[threadIdx.x] - v;
}

__global__ void add_offsets_kernel(int* __restrict__ row_start, const int* __restrict__ local_ex,
                                   const int* __restrict__ partial, int Nn) {
    int i = blockIdx.x * 256 + threadIdx.x;
    if (i < Nn) row_start[i] = local_ex[i] + partial[blockIdx.x];
}

// ---------------- edge placement: CSR by dst, with precomputed edge norm ----------------

__global__ void edge_place_kernel(const int* __restrict__ src, const int* __restrict__ dst,
                                  const int* __restrict__ row_start, int* __restrict__ cursor,
                                  const float* __restrict__ dinv,
                                  int* __restrict__ esrc, float* __restrict__ enorm, int E) {
    int e = blockIdx.x * blockDim.x + threadIdx.x;
    if (e >= E) return;
    int s = src[e], d = dst[e];
    int pos = row_start[d] + atomicAdd(&cursor[d], 1);
    esrc[pos] = s;
    enorm[pos] = dinv[s] * dinv[d];
}

// ---------------- weight split+transpose: W[K][256] f32 -> Wt_hi/Wt_lo [256][K] bf16 ----------------

__global__ void split_w_kernel(const float* __restrict__ W, bhalf* __restrict__ Wthi,
                               bhalf* __restrict__ Wtlo, int K) {
    int idx = blockIdx.x * 256 + threadIdx.x;
    if (idx >= K * 256) return;
    int k = idx >> 8, n = idx & 255;
    float w = W[idx];
    bhalf hi = f2bf_rn(w);
    bhalf lo = f2bf_rn(w - bf2f(hi));
    Wthi[n * K + k] = hi;
    Wtlo[n * K + k] = lo;
}

// ---------------- CSR gather, 128 feats, writes bf16 hi/lo split ----------------

__global__ __launch_bounds__(256)
void gather128_kernel(const float* __restrict__ x, const int* __restrict__ esrc,
                      const float* __restrict__ enorm, const int* __restrict__ row_start,
                      const int* __restrict__ degi, const float* __restrict__ dinv,
                      bhalf* __restrict__ zhi, bhalf* __restrict__ zlo, int Nn) {
    int node = blockIdx.x * 4 + (threadIdx.x >> 6);
    if (node >= Nn) return;
    int lane = threadIdx.x & 63;
    int st = row_start[node];
    int cnt = degi[node];
    float ax = 0.0f, ay = 0.0f;
    int j = 0;
    for (; j + 1 < cnt; j += 2) {
        int   s0 = esrc[st + j],  s1 = esrc[st + j + 1];
        float n0 = enorm[st + j], n1 = enorm[st + j + 1];
        float2 v0 = *reinterpret_cast<const float2*>(&x[(size_t)s0 * FIN + lane * 2]);
        float2 v1 = *reinterpret_cast<const float2*>(&x[(size_t)s1 * FIN + lane * 2]);
        ax += v0.x * n0 + v1.x * n1;
        ay += v0.y * n0 + v1.y * n1;
    }
    if (j < cnt) {
        int   s0 = esrc[st + j];
        float n0 = enorm[st + j];
        float2 v0 = *reinterpret_cast<const float2*>(&x[(size_t)s0 * FIN + lane * 2]);
        ax += v0.x * n0; ay += v0.y * n0;
    }
    float sn = dinv[node];
    sn *= sn;
    float2 xv = *reinterpret_cast<const float2*>(&x[(size_t)node * FIN + lane * 2]);
    float ox = ax + xv.x * sn, oy = ay + xv.y * sn;
    ushort2 h2 = {f2bf_rn(ox), f2bf_rn(oy)};
    ushort2 l2 = {f2bf_rn(ox - bf2f(h2.x)), f2bf_rn(oy - bf2f(h2.y))};
    *reinterpret_cast<ushort2*>(&zhi[(size_t)node * FIN + lane * 2]) = h2;
    *reinterpret_cast<ushort2*>(&zlo[(size_t)node * FIN + lane * 2]) = l2;
}

// ---------------- MFMA split-bf16 GEMM: C[M][256] = A[M][Kp] @ Bt[256][Kp]^T ----------------
// 3 passes: Ahi*Bhi + Alo*Bhi + Ahi*Blo (AloBlo ~2^-18, dropped).
// mode 1: C = gelu(acc + bias) -> split bf16 hi/lo out.  mode 0: C = acc -> f32 out.

__global__ __launch_bounds__(256)
void gemm_mfma_kernel(const bhalf* __restrict__ Ahi, const bhalf* __restrict__ Alo,
                      const bhalf* __restrict__ Bthi, const bhalf* __restrict__ Btlo,
                      const float* __restrict__ bias,
                      float* __restrict__ Cf, bhalf* __restrict__ Chi, bhalf* __restrict__ Clo,
                      int M, int Kp, int mode) {
    __shared__ bhalf As[128 * 72];   // rows x (64+8 pad): 144 B row stride (16B-aligned)
    __shared__ bhalf Bs[128 * 72];
    const int tid  = threadIdx.x;
    const int lane = tid & 63;
    const int wave = tid >> 6;
    const int quad = lane >> 4;
    const int l15  = lane & 15;
    const int wm = (wave & 1) * 64;
    const int wn = (wave >> 1) * 64;
    const int bm = blockIdx.x * 128;
    const int bn = blockIdx.y * 128;

    f32x4 acc[4][4] = {};

    for (int p = 0; p < 3; p++) {
        const bhalf* Ap = (p == 1) ? Alo : Ahi;
        const bhalf* Bp = (p == 2) ? Btlo : Bthi;
        for (int k0 = 0; k0 < Kp; k0 += 64) {
            // stage 128x64 bf16 tiles of A and Bt (both row-major, 16B chunks)
#pragma unroll
            for (int i = 0; i < 4; i++) {
                int chunk = tid + i * 256;           // 1024 chunks of 8 bf16
                int r = chunk >> 3, c16 = chunk & 7;
                int gm = bm + r;
                float4 va = make_float4(0.f, 0.f, 0.f, 0.f);
                if (gm < M) va = *reinterpret_cast<const float4*>(&Ap[(size_t)gm * Kp + k0 + c16 * 8]);
                *reinterpret_cast<float4*>(&As[r * 72 + c16 * 8]) = va;
                float4 vb = *reinterpret_cast<const float4*>(&Bp[(size_t)(bn + r) * Kp + k0 + c16 * 8]);
                *reinterpret_cast<float4*>(&Bs[r * 72 + c16 * 8]) = vb;
            }
            __syncthreads();
#pragma unroll
            for (int kk = 0; kk < 64; kk += 32) {
                bf16x8 af[4], bfr[4];
#pragma unroll
                for (int mi = 0; mi < 4; mi++)
                    af[mi] = *reinterpret_cast<const bf16x8*>(&As[(wm + mi * 16 + l15) * 72 + kk + quad * 8]);
#pragma unroll
                for (int ni = 0; ni < 4; ni++)
                    bfr[ni] = *reinterpret_cast<const bf16x8*>(&Bs[(wn + ni * 16 + l15) * 72 + kk + quad * 8]);
#pragma unroll
                for (int mi = 0; mi < 4; mi++)
#pragma unroll
                    for (int ni = 0; ni < 4; ni++)
                        acc[mi][ni] = __builtin_amdgcn_mfma_f32_16x16x32_bf16(af[mi], bfr[ni], acc[mi][ni], 0, 0, 0);
            }
            __syncthreads();
        }
    }

    // epilogue: C/D layout col = lane&15, row = quad*4 + reg
#pragma unroll
    for (int mi = 0; mi < 4; mi++) {
#pragma unroll
        for (int r = 0; r < 4; r++) {
            int row = bm + wm + mi * 16 + quad * 4 + r;
            if (row >= M) continue;
#pragma unroll
            for (int ni = 0; ni < 4; ni++) {
                int col = bn + wn + ni * 16 + l15;
                float v = acc[mi][ni][r];
                if (mode == 1) {
                    v += bias[col];
                    v = 0.5f * v * (1.0f + erff(v * 0.70710678118654752f));
                    bhalf hi = f2bf_rn(v);
                    Chi[(size_t)row * FH + col] = hi;
                    Clo[(size_t)row * FH + col] = f2bf_rn(v - bf2f(hi));
                } else {
                    Cf[(size_t)row * FH + col] = v;
                }
            }
        }
    }
}

// ---------------- CSR gather, 256 feats (conv2 post-transform) + self + bias ----------------

__global__ __launch_bounds__(256)
void gather256_kernel(const float* __restrict__ t, const int* __restrict__ esrc,
                      const float* __restrict__ enorm, const int* __restrict__ row_start,
                      const int* __restrict__ degi, const float* __restrict__ dinv,
                      const float* __restrict__ bias, float* __restrict__ h, int Nn) {
    int node = blockIdx.x * 4 + (threadIdx.x >> 6);
    if (node >= Nn) return;
    int lane = threadIdx.x & 63;
    int st = row_start[node];
    int cnt = degi[node];
    float ax = 0.0f, ay = 0.0f, az = 0.0f, aw = 0.0f;
    int j = 0;
    for (; j + 1 < cnt; j += 2) {
        int   s0 = esrc[st + j],  s1 = esrc[st + j + 1];
        float n0 = enorm[st + j], n1 = enorm[st + j + 1];
        float4 v0 = *reinterpret_cast<const float4*>(&t[(size_t)s0 * FH + lane * 4]);
        float4 v1 = *reinterpret_cast<const float4*>(&t[(size_t)s1 * FH + lane * 4]);
        ax += v0.x * n0 + v1.x * n1;
        ay += v0.y * n0 + v1.y * n1;
        az += v0.z * n0 + v1.z * n1;
        aw += v0.w * n0 + v1.w * n1;
    }
    if (j < cnt) {
        int   s0 = esrc[st + j];
        float n0 = enorm[st + j];
        float4 v0 = *reinterpret_cast<const float4*>(&t[(size_t)s0 * FH + lane * 4]);
        ax += v0.x * n0; ay += v0.y * n0; az += v0.z * n0; aw += v0.w * n0;
    }
    float sn = dinv[node];
    sn *= sn;
    float4 tv = *reinterpret_cast<const float4*>(&t[(size_t)node * FH + lane * 4]);
    float4 bv = *reinterpret_cast<const float4*>(&bias[lane * 4]);
    float4 o = {ax + tv.x * sn + bv.x, ay + tv.y * sn + bv.y,
                az + tv.z * sn + bv.z, aw + tv.w * sn + bv.w};
    *reinterpret_cast<float4*>(&h[(size_t)node * FH + lane * 4]) = o;
}

// ---------------- mean-pool (batch sorted) ----------------

__global__ __launch_bounds__(256)
void pool_kernel(const float* __restrict__ h, const int* __restrict__ batch,
                 float* __restrict__ pooled, int Nn, int npb) {
    int c = threadIdx.x;
    int n0 = blockIdx.x * npb;
    int n1 = min(n0 + npb, Nn);
    if (n0 >= n1) return;
    float acc = 0.0f;
    int cur = batch[n0];
    for (int n = n0; n < n1; n++) {
        int g = batch[n];
        if (g != cur) {
            atomicAdd(&pooled[cur * FH + c], acc);
            acc = 0.0f;
            cur = g;
        }
        acc += h[(size_t)n * FH + c];
    }
    atomicAdd(&pooled[cur * FH + c], acc);
}

// ---------------- FC head ----------------

__global__ __launch_bounds__(64)
void fc_kernel(const float* __restrict__ pooled, const float* __restrict__ cnt,
               const float* __restrict__ Wfc, const float* __restrict__ bfc,
               float* __restrict__ out) {
    int g = blockIdx.x;
    int c2 = threadIdx.x;
    float inv = 1.0f / fmaxf(cnt[g], 1.0f);
    float acc = 0.0f;
    for (int c = 0; c < FH; c++)
        acc += pooled[g * FH + c] * Wfc[c * NC + c2];
    out[g * NC + c2] = acc * inv + bfc[c2];
}

// ---------------- launch ----------------

extern "C" void kernel_launch(void* const* d_in, const int* in_sizes, int n_in,
                              void* d_out, int out_size, void* d_ws, size_t ws_size,
                              hipStream_t stream) {
    const float* x    = (const float*)d_in[0];
    const int*   ei   = (const int*)d_in[1];
    const int*   batch= (const int*)d_in[2];
    const float* W1   = (const float*)d_in[3];
    const float* b1   = (const float*)d_in[4];
    const float* W2   = (const float*)d_in[5];
    const float* b2   = (const float*)d_in[6];
    const float* Wfc  = (const float*)d_in[7];
    const float* bfc  = (const float*)d_in[8];
    float* out = (float*)d_out;

    const int* src = ei;
    const int* dst = ei + NEDGES;

    // workspace layout (~111 MB):
    // bufT [N,256] f32: aggX hi/lo pair (aliased) early, t2 later
    // bufA [N,256] f32: h1 hi/lo pair (aliased, exactly fills), then h2
    float* bufT     = (float*)d_ws;
    float* bufA     = bufT + (size_t)NNODES * FH;
    int*   esrc     = (int*)(bufA + (size_t)NNODES * FH);  // [E]
    float* enorm    = (float*)(esrc + NEDGES);             // [E]
    int*   degi     = (int*)(enorm + NEDGES);              // [N]
    int*   row_start= degi + NNODES;                       // [N]
    int*   local_ex = row_start + NNODES;                  // [N]
    int*   cursor   = local_ex + NNODES;                   // [N]
    int*   partial  = cursor + NNODES;                     // [256]
    float* dinv     = (float*)(partial + 256);             // [N]
    float* cnt      = dinv + NNODES;                       // [G]
    float* pooled   = cnt + NG;                            // [G,256]
    bhalf* w1thi    = (bhalf*)(pooled + NG * FH);          // [256,128]
    bhalf* w1tlo    = w1thi + 256 * FIN;
    bhalf* w2thi    = w1tlo + 256 * FIN;                   // [256,256]
    bhalf* w2tlo    = w2thi + 256 * FH;

    bhalf* aggXhi = (bhalf*)bufT;                          // [N,128] bf16
    bhalf* aggXlo = aggXhi + (size_t)NNODES * FIN;
    bhalf* h1hi   = (bhalf*)bufA;                          // [N,256] bf16
    bhalf* h1lo   = h1hi + (size_t)NNODES * FH;

    hipMemsetAsync(degi,   0, NNODES * sizeof(int), stream);
    hipMemsetAsync(cursor, 0, NNODES * sizeof(int), stream);
    hipMemsetAsync(pooled, 0, NG * FH * sizeof(float), stream);

    // ---- CSR build + norms ----
    degree_kernel<<<(NEDGES + 255) / 256, 256, 0, stream>>>(dst, degi, NEDGES);
    graph_bounds_kernel<<<1, 64, 0, stream>>>(batch, cnt);
    dinv_kernel<<<(NNODES + 255) / 256, 256, 0, stream>>>(degi, dinv, NNODES);
    scan_block_kernel<<<SCAN_NB, 256, 0, stream>>>(degi, local_ex, partial, NNODES);
    scan_partial_kernel<<<1, 256, 0, stream>>>(partial, SCAN_NB);
    add_offsets_kernel<<<SCAN_NB, 256, 0, stream>>>(row_start, local_ex, partial, NNODES);
    edge_place_kernel<<<(NEDGES + 255) / 256, 256, 0, stream>>>(src, dst, row_start, cursor,
                                                                dinv, esrc, enorm, NEDGES);

    // ---- weight splits (tiny) ----
    split_w_kernel<<<(FIN * 256 + 255) / 256, 256, 0, stream>>>(W1, w1thi, w1tlo, FIN);
    split_w_kernel<<<(FH  * 256 + 255) / 256, 256, 0, stream>>>(W2, w2thi, w2tlo, FH);

    int gather_blocks = (NNODES + 3) / 4;
    dim3 mgrid((NNODES + 127) / 128, 2);

    // conv1 (aggregate-first): z = Ahat*x (split bf16) ; h1 = gelu(z@W1 + b1) (split bf16)
    gather128_kernel<<<gather_blocks, 256, 0, stream>>>(x, esrc, enorm, row_start, degi,
                                                        dinv, aggXhi, aggXlo, NNODES);
    gemm_mfma_kernel<<<mgrid, 256, 0, stream>>>(aggXhi, aggXlo, w1thi, w1tlo, b1,
                                                (float*)nullptr, h1hi, h1lo, NNODES, FIN, 1);

    // conv2 (transform-first): t2 = h1@W2 (f32 out) ; h2 = Ahat*t2 + b2
    gemm_mfma_kernel<<<mgrid, 256, 0, stream>>>(h1hi, h1lo, w2thi, w2tlo, b2,
                                                bufT, (bhalf*)nullptr, (bhalf*)nullptr, NNODES, FH, 0);
    gather256_kernel<<<gather_blocks, 256, 0, stream>>>(bufT, esrc, enorm, row_start, degi,
                                                        dinv, b2, bufA, NNODES);

    // mean-pool + FC head
    pool_kernel<<<(NNODES + 63) / 64, 256, 0, stream>>>(bufA, batch, pooled, NNODES, 64);
    fc_kernel<<<NG, NC, 0, stream>>>(pooled, cnt, Wfc, bfc, out);
}

// Round 5
// 403.768 us; speedup vs baseline: 14.8034x; 1.2766x over previous
//
#include <hip/hip_runtime.h>
#include <hip/hip_bf16.h>
#include <math.h>

#define NNODES 50000
#define NEDGES 800000
#define FIN 128
#define FH 256
#define NG 64
#define NC 64
#define SCAN_NB ((NNODES + 255) / 256)

typedef unsigned short bhalf;
typedef __attribute__((ext_vector_type(8))) short bf16x8;
typedef __attribute__((ext_vector_type(4))) float f32x4;

__device__ inline bhalf f2bf_rn(float f) {
    unsigned int u = __float_as_uint(f);
    u += 0x7FFFu + ((u >> 16) & 1u);      // round-to-nearest-even
    return (bhalf)(u >> 16);
}
__device__ inline float bf2f(bhalf h) { return __uint_as_float(((unsigned int)h) << 16); }
__device__ inline float2 bfpair(unsigned int u) {   // [lo16, hi16] -> two floats
    return make_float2(__uint_as_float(u << 16), __uint_as_float(u & 0xFFFF0000u));
}

// ---------------- degree / norm ----------------

__global__ void degree_kernel(const int* __restrict__ dst, int* __restrict__ degi, int E) {
    int e = blockIdx.x * blockDim.x + threadIdx.x;
    if (e < E) atomicAdd(&degi[dst[e]], 1);
}

__global__ void dinv_kernel(const int* __restrict__ degi, float* __restrict__ dinv, int Nn) {
    int n = blockIdx.x * blockDim.x + threadIdx.x;
    if (n < Nn) dinv[n] = rsqrtf((float)degi[n] + 1.0f);
}

// ---------------- per-graph node counts via binary search (batch is sorted) ----------------

__global__ __launch_bounds__(64)
void graph_bounds_kernel(const int* __restrict__ batch, float* __restrict__ cnt) {
    int g = threadIdx.x;
    int lo = 0, hi = NNODES;
    while (lo < hi) { int mid = (lo + hi) >> 1; if (batch[mid] < g) lo = mid + 1; else hi = mid; }
    int a = lo;
    lo = 0; hi = NNODES;
    while (lo < hi) { int mid = (lo + hi) >> 1; if (batch[mid] < g + 1) lo = mid + 1; else hi = mid; }
    cnt[g] = (float)(lo - a);
}

// ---------------- 2-level exclusive scan over degi -> row_start ----------------

__global__ __launch_bounds__(256)
void scan_block_kernel(const int* __restrict__ degi, int* __restrict__ local_ex,
                       int* __restrict__ partial, int Nn) {
    __shared__ int s[256];
    int i = blockIdx.x * 256 + threadIdx.x;
    int v = (i < Nn) ? degi[i] : 0;
    s[threadIdx.x] = v;
    __syncthreads();
#pragma unroll
    for (int off = 1; off < 256; off <<= 1) {
        int t = (threadIdx.x >= off) ? s[threadIdx.x - off] : 0;
        __syncthreads();
        s[threadIdx.x] += t;
        __syncthreads();
    }
    if (i < Nn) local_ex[i] = s[threadIdx.x] - v;
    if (threadIdx.x == 255) partial[blockIdx.x] = s[255];
}

__global__ __launch_bounds__(256)
void scan_partial_kernel(int* __restrict__ partial, int nb) {
    __shared__ int s[256];
    int v = (threadIdx.x < nb) ? partial[threadIdx.x] : 0;
    s[threadIdx.x] = v;
    __syncthreads();
#pragma unroll
    for (int off = 1; off < 256; off <<= 1) {
        int t = (threadIdx.x >= off) ? s[threadIdx.x - off] : 0;
        __syncthreads();
        s[threadIdx.x] += t;
        __syncthreads();
    }
    if (threadIdx.x < nb) partial[threadIdx.x] = s[threadIdx.x] - v;
}

__global__ void add_offsets_kernel(int* __restrict__ row_start, const int* __restrict__ local_ex,
                                   const int* __restrict__ partial, int Nn) {
    int i = blockIdx.x * 256 + threadIdx.x;
    if (i < Nn) row_start[i] = local_ex[i] + partial[blockIdx.x];
}

// ---------------- edge placement: CSR by dst, with precomputed edge norm ----------------

__global__ void edge_place_kernel(const int* __restrict__ src, const int* __restrict__ dst,
                                  const int* __restrict__ row_start, int* __restrict__ cursor,
                                  const float* __restrict__ dinv,
                                  int* __restrict__ esrc, float* __restrict__ enorm, int E) {
    int e = blockIdx.x * blockDim.x + threadIdx.x;
    if (e >= E) return;
    int s = src[e], d = dst[e];
    int pos = row_start[d] + atomicAdd(&cursor[d], 1);
    esrc[pos] = s;
    enorm[pos] = dinv[s] * dinv[d];
}

// ---------------- x -> bf16 copy (vectorized: 4 elems/thread) ----------------

__global__ void split_x_kernel(const float* __restrict__ x, bhalf* __restrict__ xb, int total4) {
    int i = blockIdx.x * blockDim.x + threadIdx.x;
    if (i >= total4) return;
    float4 v = *reinterpret_cast<const float4*>(&x[i * 4]);
    ushort4 o = {f2bf_rn(v.x), f2bf_rn(v.y), f2bf_rn(v.z), f2bf_rn(v.w)};
    *reinterpret_cast<ushort4*>(&xb[i * 4]) = o;
}

// ---------------- weight round+transpose: W[K][256] f32 -> Wt [256][K] bf16 ----------------

__global__ void split_w_kernel(const float* __restrict__ W, bhalf* __restrict__ Wt, int K) {
    int idx = blockIdx.x * 256 + threadIdx.x;
    if (idx >= K * 256) return;
    int k = idx >> 8, n = idx & 255;
    Wt[n * K + k] = f2bf_rn(W[idx]);
}

// ---------------- CSR gather, 128 bf16 feats: z[n] = bf16(sum + x[n]*sn) ----------------

__global__ __launch_bounds__(256)
void gather128_kernel(const bhalf* __restrict__ xb, const int* __restrict__ esrc,
                      const float* __restrict__ enorm, const int* __restrict__ row_start,
                      const int* __restrict__ degi, const float* __restrict__ dinv,
                      bhalf* __restrict__ z, int Nn) {
    int node = blockIdx.x * 4 + (threadIdx.x >> 6);
    if (node >= Nn) return;
    int lane = threadIdx.x & 63;
    int st = row_start[node];
    int cnt = degi[node];
    float ax = 0.0f, ay = 0.0f;
    int j = 0;
    for (; j + 1 < cnt; j += 2) {
        int   s0 = esrc[st + j],  s1 = esrc[st + j + 1];
        float n0 = enorm[st + j], n1 = enorm[st + j + 1];
        unsigned int u0 = *reinterpret_cast<const unsigned int*>(&xb[(size_t)s0 * FIN + lane * 2]);
        unsigned int u1 = *reinterpret_cast<const unsigned int*>(&xb[(size_t)s1 * FIN + lane * 2]);
        float2 v0 = bfpair(u0), v1 = bfpair(u1);
        ax += v0.x * n0 + v1.x * n1;
        ay += v0.y * n0 + v1.y * n1;
    }
    if (j < cnt) {
        int   s0 = esrc[st + j];
        float n0 = enorm[st + j];
        float2 v0 = bfpair(*reinterpret_cast<const unsigned int*>(&xb[(size_t)s0 * FIN + lane * 2]));
        ax += v0.x * n0; ay += v0.y * n0;
    }
    float sn = dinv[node];
    sn *= sn;
    float2 xv = bfpair(*reinterpret_cast<const unsigned int*>(&xb[(size_t)node * FIN + lane * 2]));
    ushort2 o = {f2bf_rn(ax + xv.x * sn), f2bf_rn(ay + xv.y * sn)};
    *reinterpret_cast<ushort2*>(&z[(size_t)node * FIN + lane * 2]) = o;
}

// ---------------- MFMA bf16 GEMM: C[M][256] = A[M][Kp] @ Bt[256][Kp]^T, bf16 out ----------------
// mode 1: C = bf16(gelu(acc + bias)).  mode 0: C = bf16(acc).

__global__ __launch_bounds__(256)
void gemm_mfma_kernel(const bhalf* __restrict__ A, const bhalf* __restrict__ Bt,
                      const float* __restrict__ bias, bhalf* __restrict__ C,
                      int M, int Kp, int mode) {
    __shared__ bhalf As[128 * 72];   // rows x (64+8 pad): 144 B row stride (16B-aligned)
    __shared__ bhalf Bs[128 * 72];
    const int tid  = threadIdx.x;
    const int lane = tid & 63;
    const int wave = tid >> 6;
    const int quad = lane >> 4;
    const int l15  = lane & 15;
    const int wm = (wave & 1) * 64;
    const int wn = (wave >> 1) * 64;
    const int bm = blockIdx.x * 128;
    const int bn = blockIdx.y * 128;

    f32x4 acc[4][4] = {};

    for (int k0 = 0; k0 < Kp; k0 += 64) {
#pragma unroll
        for (int i = 0; i < 4; i++) {
            int chunk = tid + i * 256;           // 1024 chunks of 8 bf16
            int r = chunk >> 3, c16 = chunk & 7;
            int gm = bm + r;
            float4 va = make_float4(0.f, 0.f, 0.f, 0.f);
            if (gm < M) va = *reinterpret_cast<const float4*>(&A[(size_t)gm * Kp + k0 + c16 * 8]);
            *reinterpret_cast<float4*>(&As[r * 72 + c16 * 8]) = va;
            float4 vb = *reinterpret_cast<const float4*>(&Bt[(size_t)(bn + r) * Kp + k0 + c16 * 8]);
            *reinterpret_cast<float4*>(&Bs[r * 72 + c16 * 8]) = vb;
        }
        __syncthreads();
#pragma unroll
        for (int kk = 0; kk < 64; kk += 32) {
            bf16x8 af[4], bfr[4];
#pragma unroll
            for (int mi = 0; mi < 4; mi++)
                af[mi] = *reinterpret_cast<const bf16x8*>(&As[(wm + mi * 16 + l15) * 72 + kk + quad * 8]);
#pragma unroll
            for (int ni = 0; ni < 4; ni++)
                bfr[ni] = *reinterpret_cast<const bf16x8*>(&Bs[(wn + ni * 16 + l15) * 72 + kk + quad * 8]);
#pragma unroll
            for (int mi = 0; mi < 4; mi++)
#pragma unroll
                for (int ni = 0; ni < 4; ni++)
                    acc[mi][ni] = __builtin_amdgcn_mfma_f32_16x16x32_bf16(af[mi], bfr[ni], acc[mi][ni], 0, 0, 0);
        }
        __syncthreads();
    }

    // epilogue: C/D layout col = lane&15, row = quad*4 + reg
#pragma unroll
    for (int mi = 0; mi < 4; mi++) {
#pragma unroll
        for (int r = 0; r < 4; r++) {
            int row = bm + wm + mi * 16 + quad * 4 + r;
            if (row >= M) continue;
#pragma unroll
            for (int ni = 0; ni < 4; ni++) {
                int col = bn + wn + ni * 16 + l15;
                float v = acc[mi][ni][r];
                if (mode == 1) {
                    v += bias[col];
                    v = 0.5f * v * (1.0f + erff(v * 0.70710678118654752f));
                }
                C[(size_t)row * FH + col] = f2bf_rn(v);
            }
        }
    }
}

// ---------------- CSR gather, 256 bf16 feats + self + bias -> h2 f32 ----------------

__global__ __launch_bounds__(256)
void gather256_kernel(const bhalf* __restrict__ t, const int* __restrict__ esrc,
                      const float* __restrict__ enorm, const int* __restrict__ row_start,
                      const int* __restrict__ degi, const float* __restrict__ dinv,
                      const float* __restrict__ bias, float* __restrict__ h, int Nn) {
    int node = blockIdx.x * 4 + (threadIdx.x >> 6);
    if (node >= Nn) return;
    int lane = threadIdx.x & 63;
    int st = row_start[node];
    int cnt = degi[node];
    float ax = 0.0f, ay = 0.0f, az = 0.0f, aw = 0.0f;
    int j = 0;
    for (; j + 1 < cnt; j += 2) {
        int   s0 = esrc[st + j],  s1 = esrc[st + j + 1];
        float n0 = enorm[st + j], n1 = enorm[st + j + 1];
        uint2 u0 = *reinterpret_cast<const uint2*>(&t[(size_t)s0 * FH + lane * 4]);
        uint2 u1 = *reinterpret_cast<const uint2*>(&t[(size_t)s1 * FH + lane * 4]);
        float2 a0 = bfpair(u0.x), b0 = bfpair(u0.y);
        float2 a1 = bfpair(u1.x), b1 = bfpair(u1.y);
        ax += a0.x * n0 + a1.x * n1;
        ay += a0.y * n0 + a1.y * n1;
        az += b0.x * n0 + b1.x * n1;
        aw += b0.y * n0 + b1.y * n1;
    }
    if (j < cnt) {
        int   s0 = esrc[st + j];
        float n0 = enorm[st + j];
        uint2 u0 = *reinterpret_cast<const uint2*>(&t[(size_t)s0 * FH + lane * 4]);
        float2 a0 = bfpair(u0.x), b0 = bfpair(u0.y);
        ax += a0.x * n0; ay += a0.y * n0; az += b0.x * n0; aw += b0.y * n0;
    }
    float sn = dinv[node];
    sn *= sn;
    uint2 uv = *reinterpret_cast<const uint2*>(&t[(size_t)node * FH + lane * 4]);
    float2 ta = bfpair(uv.x), tb = bfpair(uv.y);
    float4 bv = *reinterpret_cast<const float4*>(&bias[lane * 4]);
    float4 o = {ax + ta.x * sn + bv.x, ay + ta.y * sn + bv.y,
                az + tb.x * sn + bv.z, aw + tb.y * sn + bv.w};
    *reinterpret_cast<float4*>(&h[(size_t)node * FH + lane * 4]) = o;
}

// ---------------- mean-pool (batch sorted) ----------------

__global__ __launch_bounds__(256)
void pool_kernel(const float* __restrict__ h, const int* __restrict__ batch,
                 float* __restrict__ pooled, int Nn, int npb) {
    int c = threadIdx.x;
    int n0 = blockIdx.x * npb;
    int n1 = min(n0 + npb, Nn);
    if (n0 >= n1) return;
    float acc = 0.0f;
    int cur = batch[n0];
    for (int n = n0; n < n1; n++) {
        int g = batch[n];
        if (g != cur) {
            atomicAdd(&pooled[cur * FH + c], acc);
            acc = 0.0f;
            cur = g;
        }
        acc += h[(size_t)n * FH + c];
    }
    atomicAdd(&pooled[cur * FH + c], acc);
}

// ---------------- FC head ----------------

__global__ __launch_bounds__(64)
void fc_kernel(const float* __restrict__ pooled, const float* __restrict__ cnt,
               const float* __restrict__ Wfc, const float* __restrict__ bfc,
               float* __restrict__ out) {
    int g = blockIdx.x;
    int c2 = threadIdx.x;
    float inv = 1.0f / fmaxf(cnt[g], 1.0f);
    float acc = 0.0f;
    for (int c = 0; c < FH; c++)
        acc += pooled[g * FH + c] * Wfc[c * NC + c2];
    out[g * NC + c2] = acc * inv + bfc[c2];
}

// ---------------- launch ----------------

extern "C" void kernel_launch(void* const* d_in, const int* in_sizes, int n_in,
                              void* d_out, int out_size, void* d_ws, size_t ws_size,
                              hipStream_t stream) {
    const float* x    = (const float*)d_in[0];
    const int*   ei   = (const int*)d_in[1];
    const int*   batch= (const int*)d_in[2];
    const float* W1   = (const float*)d_in[3];
    const float* b1   = (const float*)d_in[4];
    const float* W2   = (const float*)d_in[5];
    const float* b2   = (const float*)d_in[6];
    const float* Wfc  = (const float*)d_in[7];
    const float* bfc  = (const float*)d_in[8];
    float* out = (float*)d_out;

    const int* src = ei;
    const int* dst = ei + NEDGES;

    // workspace (~111 MB), heavy aliasing on stream order:
    // bufT [N,256]f32: xb[N,128]bf16 + z[N,128]bf16 early; t2[N,256]bf16 later (xb,z dead)
    // bufA [N,256]f32: h1[N,256]bf16 (first half) early; h2[N,256]f32 later (h1 dead)
    float* bufT     = (float*)d_ws;
    float* bufA     = bufT + (size_t)NNODES * FH;
    int*   esrc     = (int*)(bufA + (size_t)NNODES * FH);  // [E]
    float* enorm    = (float*)(esrc + NEDGES);             // [E]
    int*   degi     = (int*)(enorm + NEDGES);              // [N]
    int*   row_start= degi + NNODES;                       // [N]
    int*   local_ex = row_start + NNODES;                  // [N]
    int*   cursor   = local_ex + NNODES;                   // [N]
    int*   partial  = cursor + NNODES;                     // [256]
    float* dinv     = (float*)(partial + 256);             // [N]
    float* cnt      = dinv + NNODES;                       // [G]
    float* pooled   = cnt + NG;                            // [G,256]
    bhalf* w1t      = (bhalf*)(pooled + NG * FH);          // [256,128]
    bhalf* w2t      = w1t + 256 * FIN;                     // [256,256]

    bhalf* xb = (bhalf*)bufT;                              // [N,128] bf16
    bhalf* zb = xb + (size_t)NNODES * FIN;                 // [N,128] bf16
    bhalf* t2 = (bhalf*)bufT;                              // [N,256] bf16 (overlays xb+zb)
    bhalf* h1 = (bhalf*)bufA;                              // [N,256] bf16
    float* h2 = bufA;                                      // [N,256] f32 (overlays h1)

    hipMemsetAsync(degi,   0, NNODES * sizeof(int), stream);
    hipMemsetAsync(cursor, 0, NNODES * sizeof(int), stream);
    hipMemsetAsync(pooled, 0, NG * FH * sizeof(float), stream);

    // ---- CSR build + norms ----
    degree_kernel<<<(NEDGES + 255) / 256, 256, 0, stream>>>(dst, degi, NEDGES);
    graph_bounds_kernel<<<1, 64, 0, stream>>>(batch, cnt);
    dinv_kernel<<<(NNODES + 255) / 256, 256, 0, stream>>>(degi, dinv, NNODES);
    scan_block_kernel<<<SCAN_NB, 256, 0, stream>>>(degi, local_ex, partial, NNODES);
    scan_partial_kernel<<<1, 256, 0, stream>>>(partial, SCAN_NB);
    add_offsets_kernel<<<SCAN_NB, 256, 0, stream>>>(row_start, local_ex, partial, NNODES);
    edge_place_kernel<<<(NEDGES + 255) / 256, 256, 0, stream>>>(src, dst, row_start, cursor,
                                                                dinv, esrc, enorm, NEDGES);

    // ---- bf16 conversions (tiny) ----
    split_x_kernel<<<(NNODES * FIN / 4 + 255) / 256, 256, 0, stream>>>(x, xb, NNODES * FIN / 4);
    split_w_kernel<<<(FIN * 256 + 255) / 256, 256, 0, stream>>>(W1, w1t, FIN);
    split_w_kernel<<<(FH  * 256 + 255) / 256, 256, 0, stream>>>(W2, w2t, FH);

    int gather_blocks = (NNODES + 3) / 4;
    dim3 mgrid((NNODES + 127) / 128, 2);

    // conv1 (aggregate-first): z = bf16(Ahat*x) ; h1 = bf16(gelu(z@W1 + b1))
    gather128_kernel<<<gather_blocks, 256, 0, stream>>>(xb, esrc, enorm, row_start, degi,
                                                        dinv, zb, NNODES);
    gemm_mfma_kernel<<<mgrid, 256, 0, stream>>>(zb, w1t, b1, h1, NNODES, FIN, 1);

    // conv2 (transform-first): t2 = bf16(h1@W2) ; h2 = Ahat*t2 + b2 (f32)
    gemm_mfma_kernel<<<mgrid, 256, 0, stream>>>(h1, w2t, b2, t2, NNODES, FH, 0);
    gather256_kernel<<<gather_blocks, 256, 0, stream>>>(t2, esrc, enorm, row_start, degi,
                                                        dinv, b2, h2, NNODES);

    // mean-pool + FC head
    pool_kernel<<<(NNODES + 63) / 64, 256, 0, stream>>>(h2, batch, pooled, NNODES, 64);
    fc_kernel<<<NG, NC, 0, stream>>>(pooled, cnt, Wfc, bfc, out);
}